// Round 2
// baseline (733.208 us; speedup 1.0000x reference)
//
#include <hip/hip_runtime.h>
#include <hip/hip_bf16.h>

// Shapes (fixed by the reference): b=2,t=8,l=1024,c=256,h=8,d=32
//   tokens NTOK = 16384, head-instances BTH = 128
// Inputs/outputs: float32 (per reference). ws intermediates: bf16.
// ws layout (bf16): qn | kn | vn | xatt, each NTOK*C = 4194304 elems -> 32MB
// Intermediate layout [bth, l, d]: idx = ((bt*8 + h)*1024 + l)*32 + d

#define NTOK  16384
#define CDIM  256
#define LSEQ  1024
#define HEADS 8
#define DHEAD 32
#define ATTN_SCALE 0.17677669529663687f  // 1/sqrt(32)

__device__ __forceinline__ void unpack8(uint4 w, float* o) {
  o[0] = __uint_as_float(w.x << 16);
  o[1] = __uint_as_float(w.x & 0xffff0000u);
  o[2] = __uint_as_float(w.y << 16);
  o[3] = __uint_as_float(w.y & 0xffff0000u);
  o[4] = __uint_as_float(w.z << 16);
  o[5] = __uint_as_float(w.z & 0xffff0000u);
  o[6] = __uint_as_float(w.w << 16);
  o[7] = __uint_as_float(w.w & 0xffff0000u);
}

// ---------------------------------------------------------------------------
// Kernel 1: y = x @ W^T + b, per-head L2-normalize, write [bth,l,d] bf16.
// 32 tokens/block, 256 threads. Thread (c0=tid&63, g=tid>>6) computes
// channels c0+{0,64,128,192} for tokens g*8..g*8+7. Inputs f32.
// ---------------------------------------------------------------------------
__global__ __launch_bounds__(256, 4)
void proj_norm_kernel(const float* __restrict__ x,
                      const float* __restrict__ W,
                      const float* __restrict__ bias,
                      __hip_bfloat16* __restrict__ out) {
  __shared__ __align__(16) float xs[32][CDIM];  // 32KB
  const int tid = threadIdx.x;
  const int tokbase = blockIdx.x * 32;

  // stage 32 token rows (8192 f32 = 2048 float4), coalesced
  const float4* xg = (const float4*)(x + (size_t)tokbase * CDIM);
  float4* xsv = (float4*)&xs[0][0];
#pragma unroll
  for (int u = 0; u < 8; ++u) {
    int idx = u * 256 + tid;
    xsv[idx] = xg[idx];
  }
  __syncthreads();

  const int c0 = tid & 63;
  const int g  = tid >> 6;

  float acc[4][8];
#pragma unroll
  for (int k = 0; k < 4; ++k)
#pragma unroll
    for (int t = 0; t < 8; ++t) acc[k][t] = 0.f;

  for (int i = 0; i < CDIM; i += 8) {
    float wf[4][8];
#pragma unroll
    for (int k = 0; k < 4; ++k) {
      const float* wr = W + (size_t)(c0 + 64 * k) * CDIM + i;
      *(float4*)&wf[k][0] = *(const float4*)wr;
      *(float4*)&wf[k][4] = *(const float4*)(wr + 4);
    }
#pragma unroll
    for (int t = 0; t < 8; ++t) {
      const float* xr = &xs[g * 8 + t][i];
      float4 xa = *(const float4*)xr;
      float4 xb = *(const float4*)(xr + 4);
#pragma unroll
      for (int k = 0; k < 4; ++k) {
        acc[k][t] += wf[k][0] * xa.x + wf[k][1] * xa.y + wf[k][2] * xa.z +
                     wf[k][3] * xa.w + wf[k][4] * xb.x + wf[k][5] * xb.y +
                     wf[k][6] * xb.z + wf[k][7] * xb.w;
      }
    }
  }

  // bias + per-head L2 norm (32 channels of a head live in one 32-lane half)
#pragma unroll
  for (int k = 0; k < 4; ++k) {
    float bv = bias[c0 + 64 * k];
    int h = 2 * k + (c0 >> 5);
    int d = c0 & 31;
#pragma unroll
    for (int t = 0; t < 8; ++t) {
      float v = acc[k][t] + bv;
      float ss = v * v;
      ss += __shfl_xor(ss, 1, 32);
      ss += __shfl_xor(ss, 2, 32);
      ss += __shfl_xor(ss, 4, 32);
      ss += __shfl_xor(ss, 8, 32);
      ss += __shfl_xor(ss, 16, 32);
      v /= fmaxf(sqrtf(ss), 1e-12f);
      int tok = tokbase + g * 8 + t;
      int bt = tok >> 10, l = tok & 1023;
      out[(((size_t)bt * HEADS + h) * LSEQ + l) * DHEAD + d] = __float2bfloat16(v);
    }
  }
}

// ---------------------------------------------------------------------------
// Kernel 2: attention per head (bf16 in ws). Block handles 256 query rows of
// one head. Thread (p=tid>>1, s=tid&1) owns rows {rowbase+p, rowbase+p+128}
// and keys [s*512, s*512+512). Scores are tiny (|s|<=0.177) so softmax needs
// no max-subtraction: partial (lsum, acc) combine across the key split with a
// single shfl_xor(1) — exact.
// ---------------------------------------------------------------------------
__global__ __launch_bounds__(256, 2)
void attn_kernel(const __hip_bfloat16* __restrict__ qn,
                 const __hip_bfloat16* __restrict__ kn,
                 const __hip_bfloat16* __restrict__ vn,
                 __hip_bfloat16* __restrict__ xo) {
  __shared__ __align__(16) float kbuf[2][64][DHEAD];  // 16KB
  __shared__ __align__(16) float vbuf[2][64][DHEAD];  // 16KB
  const int tid = threadIdx.x;
  const int bth = blockIdx.x >> 2;
  const int rowbase = (blockIdx.x & 3) << 8;
  const int s = tid & 1;
  const int p = tid >> 1;
  const size_t hb = (size_t)bth * (LSEQ * DHEAD);

  const int r0 = rowbase + p;
  const int r1 = rowbase + p + 128;

  float qr[2][DHEAD];
  {
    const uint4* q0 = (const uint4*)(qn + hb + (size_t)r0 * DHEAD);
    const uint4* q1 = (const uint4*)(qn + hb + (size_t)r1 * DHEAD);
#pragma unroll
    for (int u = 0; u < 4; ++u) {
      unpack8(q0[u], &qr[0][u * 8]);
      unpack8(q1[u], &qr[1][u * 8]);
    }
  }

  float acc[2][DHEAD];
#pragma unroll
  for (int r = 0; r < 2; ++r)
#pragma unroll
    for (int dd = 0; dd < DHEAD; ++dd) acc[r][dd] = 0.f;
  float lsum[2] = {0.f, 0.f};

  for (int it = 0; it < 8; ++it) {
    __syncthreads();  // previous chunk fully consumed before overwrite
    // stage 4 chunks (k/v x key-half), 256 uint4 each, coalesced
#pragma unroll
    for (int u = 0; u < 4; ++u) {
      int half = u & 1, isv = u >> 1;
      int kstart = half * 512 + it * 64;
      const uint4* sp =
          (const uint4*)((isv ? vn : kn) + hb + (size_t)kstart * DHEAD);
      uint4 wv = sp[tid];
      float* db = (isv ? &vbuf[half][0][0] : &kbuf[half][0][0]) + tid * 8;
      unpack8(wv, db);
    }
    __syncthreads();

    for (int j = 0; j < 64; ++j) {
      const float4* kr = (const float4*)kbuf[s][j];
      float d0 = 0.f, d1 = 0.f;
#pragma unroll
      for (int f = 0; f < 8; ++f) {
        float4 kv = kr[f];
        d0 += qr[0][4 * f + 0] * kv.x + qr[0][4 * f + 1] * kv.y +
              qr[0][4 * f + 2] * kv.z + qr[0][4 * f + 3] * kv.w;
        d1 += qr[1][4 * f + 0] * kv.x + qr[1][4 * f + 1] * kv.y +
              qr[1][4 * f + 2] * kv.z + qr[1][4 * f + 3] * kv.w;
      }
      float p0 = __expf(d0 * ATTN_SCALE);
      float p1 = __expf(d1 * ATTN_SCALE);
      lsum[0] += p0;
      lsum[1] += p1;
      const float4* vr = (const float4*)vbuf[s][j];
#pragma unroll
      for (int f = 0; f < 8; ++f) {
        float4 vv = vr[f];
        acc[0][4 * f + 0] += p0 * vv.x;
        acc[0][4 * f + 1] += p0 * vv.y;
        acc[0][4 * f + 2] += p0 * vv.z;
        acc[0][4 * f + 3] += p0 * vv.w;
        acc[1][4 * f + 0] += p1 * vv.x;
        acc[1][4 * f + 1] += p1 * vv.y;
        acc[1][4 * f + 2] += p1 * vv.z;
        acc[1][4 * f + 3] += p1 * vv.w;
      }
    }
  }

  // combine key-split partials across adjacent lanes (exact: no max rescale)
#pragma unroll
  for (int r = 0; r < 2; ++r) {
    lsum[r] += __shfl_xor(lsum[r], 1);
#pragma unroll
    for (int dd = 0; dd < DHEAD; ++dd) acc[r][dd] += __shfl_xor(acc[r][dd], 1);
  }

  // lane s writes row r_s
  const int wr = s ? r1 : r0;
  const float inv = 1.0f / lsum[s];
  __hip_bfloat16* dst = xo + hb + (size_t)wr * DHEAD;
#pragma unroll
  for (int dd = 0; dd < DHEAD; ++dd)
    dst[dd] = __float2bfloat16(acc[s][dd] * inv);
}

// ---------------------------------------------------------------------------
// Kernel 3: out = xatt @ Wm^T + bm + residual(q), f32 out. Same GEMM
// structure as K1; xatt gathered from bf16 [bth,l,d] back to [token, c].
// ---------------------------------------------------------------------------
__global__ __launch_bounds__(256, 4)
void out_proj_kernel(const __hip_bfloat16* __restrict__ xatt,
                     const float* __restrict__ Wm,
                     const float* __restrict__ bm,
                     const float* __restrict__ resid,
                     float* __restrict__ out) {
  __shared__ __align__(16) float xs[32][CDIM];
  const int tid = threadIdx.x;
  const int tokbase = blockIdx.x * 32;

#pragma unroll
  for (int u = 0; u < 4; ++u) {
    int idx = u * 256 + tid;   // 8-elem (uint4 of bf16) unit
    int tok = idx >> 5;        // local token
    int i = (idx & 31) * 8;    // channel start (within one head: 8 | 32)
    int gtok = tokbase + tok;
    int bt = gtok >> 10, l = gtok & 1023;
    int h = i >> 5, d = i & 31;
    const uint4* sp =
        (const uint4*)(xatt + (((size_t)bt * HEADS + h) * LSEQ + l) * DHEAD + d);
    unpack8(sp[0], &xs[tok][i]);
  }
  __syncthreads();

  const int c0 = tid & 63;
  const int g  = tid >> 6;

  float acc[4][8];
#pragma unroll
  for (int k = 0; k < 4; ++k)
#pragma unroll
    for (int t = 0; t < 8; ++t) acc[k][t] = 0.f;

  for (int i = 0; i < CDIM; i += 8) {
    float wf[4][8];
#pragma unroll
    for (int k = 0; k < 4; ++k) {
      const float* wr = Wm + (size_t)(c0 + 64 * k) * CDIM + i;
      *(float4*)&wf[k][0] = *(const float4*)wr;
      *(float4*)&wf[k][4] = *(const float4*)(wr + 4);
    }
#pragma unroll
    for (int t = 0; t < 8; ++t) {
      const float* xr = &xs[g * 8 + t][i];
      float4 xa = *(const float4*)xr;
      float4 xb = *(const float4*)(xr + 4);
#pragma unroll
      for (int k = 0; k < 4; ++k) {
        acc[k][t] += wf[k][0] * xa.x + wf[k][1] * xa.y + wf[k][2] * xa.z +
                     wf[k][3] * xa.w + wf[k][4] * xb.x + wf[k][5] * xb.y +
                     wf[k][6] * xb.z + wf[k][7] * xb.w;
      }
    }
  }

#pragma unroll
  for (int k = 0; k < 4; ++k) {
    int ch = c0 + 64 * k;
    float bv = bm[ch];
#pragma unroll
    for (int t = 0; t < 8; ++t) {
      int tok = tokbase + g * 8 + t;
      float v = acc[k][t] + bv + resid[(size_t)tok * CDIM + ch];
      out[(size_t)tok * CDIM + ch] = v;
    }
  }
}

extern "C" void kernel_launch(void* const* d_in, const int* in_sizes, int n_in,
                              void* d_out, int out_size, void* d_ws,
                              size_t ws_size, hipStream_t stream) {
  const float* q  = (const float*)d_in[0];
  const float* k  = (const float*)d_in[1];
  const float* v  = (const float*)d_in[2];
  const float* Wq = (const float*)d_in[3];
  const float* bq = (const float*)d_in[4];
  const float* Wk = (const float*)d_in[5];
  const float* bk = (const float*)d_in[6];
  const float* Wv = (const float*)d_in[7];
  const float* bv = (const float*)d_in[8];
  const float* Wm = (const float*)d_in[9];
  const float* bm = (const float*)d_in[10];
  float* outp = (float*)d_out;

  __hip_bfloat16* ws = (__hip_bfloat16*)d_ws;
  const size_t TENS = (size_t)NTOK * CDIM;  // 4194304 elems
  __hip_bfloat16* qn = ws;
  __hip_bfloat16* kn = ws + TENS;
  __hip_bfloat16* vn = ws + 2 * TENS;
  __hip_bfloat16* xa = ws + 3 * TENS;

  dim3 blk(256);
  proj_norm_kernel<<<dim3(NTOK / 32), blk, 0, stream>>>(q, Wq, bq, qn);
  proj_norm_kernel<<<dim3(NTOK / 32), blk, 0, stream>>>(k, Wk, bk, kn);
  proj_norm_kernel<<<dim3(NTOK / 32), blk, 0, stream>>>(v, Wv, bv, vn);
  attn_kernel<<<dim3(512), blk, 0, stream>>>(qn, kn, vn, xa);
  out_proj_kernel<<<dim3(NTOK / 32), blk, 0, stream>>>(xa, Wm, bm, q, outp);
}

// Round 3
// 424.963 us; speedup vs baseline: 1.7253x; 1.7253x over previous
//
#include <hip/hip_runtime.h>
#include <hip/hip_bf16.h>

// Shapes: b=2,t=8,l=1024,c=256,h=8,d=32 -> NTOK=16384, BTH=128
// Inputs/outputs: float32. ws intermediates: _Float16.
// ws layout (f16): qn | kn | vt | xatt, each 4194304 elems (8MB) -> 32MB
//   qn/kn/xatt: [bth][l][32]; vt TRANSPOSED: [bth][32][l]
// qn is pre-scaled by log2(e)/sqrt(32) so attn uses exp2 directly.

#define NTOK  16384
#define CDIM  256
#define LSEQ  1024
#define HEADS 8
#define DHEAD 32

typedef _Float16 f16;
typedef __attribute__((ext_vector_type(4))) _Float16 f16x4;
typedef __attribute__((ext_vector_type(8))) _Float16 f16x8;
typedef __attribute__((ext_vector_type(4))) float f32x4;

#define QSCALE (0.17677669529663687f * 1.4426950408889634f)  // 1/sqrt(32)*log2e

// ---------------------------------------------------------------------------
// Kernel 1: y = x @ W^T + b, per-head L2-normalize (+scale), write f16.
// transposed=0: out[bth][l][d]; transposed=1: out[bth][d][l] (for V).
// ---------------------------------------------------------------------------
__global__ __launch_bounds__(256, 4)
void proj_norm_kernel(const float* __restrict__ x,
                      const float* __restrict__ W,
                      const float* __restrict__ bias,
                      f16* __restrict__ out,
                      float outScale, int transposed) {
  __shared__ __align__(16) float xs[32][CDIM];  // 32KB
  const int tid = threadIdx.x;
  const int tokbase = blockIdx.x * 32;

  const float4* xg = (const float4*)(x + (size_t)tokbase * CDIM);
  float4* xsv = (float4*)&xs[0][0];
#pragma unroll
  for (int u = 0; u < 8; ++u) {
    int idx = u * 256 + tid;
    xsv[idx] = xg[idx];
  }
  __syncthreads();

  const int c0 = tid & 63;
  const int g  = tid >> 6;

  float acc[4][8];
#pragma unroll
  for (int k = 0; k < 4; ++k)
#pragma unroll
    for (int t = 0; t < 8; ++t) acc[k][t] = 0.f;

  for (int i = 0; i < CDIM; i += 8) {
    float wf[4][8];
#pragma unroll
    for (int k = 0; k < 4; ++k) {
      const float* wr = W + (size_t)(c0 + 64 * k) * CDIM + i;
      *(float4*)&wf[k][0] = *(const float4*)wr;
      *(float4*)&wf[k][4] = *(const float4*)(wr + 4);
    }
#pragma unroll
    for (int t = 0; t < 8; ++t) {
      const float* xr = &xs[g * 8 + t][i];
      float4 xa = *(const float4*)xr;
      float4 xb = *(const float4*)(xr + 4);
#pragma unroll
      for (int k = 0; k < 4; ++k) {
        acc[k][t] += wf[k][0] * xa.x + wf[k][1] * xa.y + wf[k][2] * xa.z +
                     wf[k][3] * xa.w + wf[k][4] * xb.x + wf[k][5] * xb.y +
                     wf[k][6] * xb.z + wf[k][7] * xb.w;
      }
    }
  }

#pragma unroll
  for (int k = 0; k < 4; ++k) {
    float bv = bias[c0 + 64 * k];
    int h = 2 * k + (c0 >> 5);
    int d = c0 & 31;
#pragma unroll
    for (int t = 0; t < 8; ++t) {
      float v = acc[k][t] + bv;
      float ss = v * v;
      ss += __shfl_xor(ss, 1, 32);
      ss += __shfl_xor(ss, 2, 32);
      ss += __shfl_xor(ss, 4, 32);
      ss += __shfl_xor(ss, 8, 32);
      ss += __shfl_xor(ss, 16, 32);
      v = v / fmaxf(sqrtf(ss), 1e-12f) * outScale;
      int tok = tokbase + g * 8 + t;
      int bt = tok >> 10, l = tok & 1023;
      size_t bh = (size_t)bt * HEADS + h;
      size_t oi = transposed ? (bh * DHEAD + d) * LSEQ + l
                             : (bh * LSEQ + l) * DHEAD + d;
      out[oi] = (f16)v;
    }
  }
}

// ---------------------------------------------------------------------------
// Kernel 2: MFMA attention. Grid 512 blocks x 256 thr; block = 4 waves, one
// head-quarter (256 q rows); wave owns 64 q rows (4 q-tiles of 16).
// Per 128-key chunk: K/V frags -> registers (read once per wave); per
// (q-tile, 32-key subchunk): S^T = K*Q^T via mfma_16x16x32_f16 (k=d=32),
// exp2 (qn prescaled; no max needed: |score_log2|<=0.26), P packed f16 ->
// wave-private LDS (b64 writes / b128 A-frag reads, row pad 40), then
// O += P*V via 2 mfmas (V globally transposed: [bth][d][l]).
// No __syncthreads anywhere (within-wave LDS round-trip only).
// ---------------------------------------------------------------------------
__global__ __launch_bounds__(256, 2)
void attn_mfma_kernel(const f16* __restrict__ qn,
                      const f16* __restrict__ kn,
                      const f16* __restrict__ vt,
                      f16* __restrict__ xo) {
  __shared__ f16 pbuf[4][16 * 40];  // 5KB, per-wave private 16x40
  const int tid  = threadIdx.x;
  const int wave = tid >> 6, lane = tid & 63;
  const int quad = lane >> 4, l16 = lane & 15;
  const int bth  = blockIdx.x >> 2;
  const int qbase = ((blockIdx.x & 3) << 8) + wave * 64;
  const size_t hb = (size_t)bth * (LSEQ * DHEAD);
  f16* pw = &pbuf[wave][0];

  // Q B-frags: B[kk=d][n=q] = Q[q=l16][d=quad*8+j], 16B contiguous
  f16x8 qf[4];
#pragma unroll
  for (int qt = 0; qt < 4; ++qt)
    qf[qt] = *(const f16x8*)(qn + hb +
                             (size_t)(qbase + qt * 16 + l16) * DHEAD + quad * 8);

  f32x4 oacc[4][2];
  float lsum[4];
#pragma unroll
  for (int qt = 0; qt < 4; ++qt) {
    lsum[qt] = 0.f;
#pragma unroll
    for (int h = 0; h < 2; ++h) oacc[qt][h] = (f32x4){0.f, 0.f, 0.f, 0.f};
  }

  for (int kb = 0; kb < LSEQ; kb += 128) {
    // K A-frags: A[m=key][kk=d] = K[kb+t*16+l16][quad*8+j]
    f16x8 kf[8];
#pragma unroll
    for (int t = 0; t < 8; ++t)
      kf[t] = *(const f16x8*)(kn + hb +
                              (size_t)(kb + t * 16 + l16) * DHEAD + quad * 8);
    // V B-frags: B[kk=key][n=d] = vt[h*16+l16][kb+c*32+quad*8+j]
    f16x8 vf[8];
#pragma unroll
    for (int c = 0; c < 4; ++c)
#pragma unroll
      for (int h = 0; h < 2; ++h)
        vf[c * 2 + h] = *(const f16x8*)(vt + hb +
                                        (size_t)(h * 16 + l16) * LSEQ + kb +
                                        c * 32 + quad * 8);

#pragma unroll
    for (int qt = 0; qt < 4; ++qt) {
#pragma unroll
      for (int c = 0; c < 4; ++c) {
        const f32x4 z = {0.f, 0.f, 0.f, 0.f};
        // S^T tiles: D[row=key=quad*4+r][col=q=l16]
        f32x4 s0 = __builtin_amdgcn_mfma_f32_16x16x32_f16(kf[c * 2 + 0],
                                                          qf[qt], z, 0, 0, 0);
        f32x4 s1 = __builtin_amdgcn_mfma_f32_16x16x32_f16(kf[c * 2 + 1],
                                                          qf[qt], z, 0, 0, 0);
        f16x4 p0, p1;
        float ls = 0.f;
#pragma unroll
        for (int r = 0; r < 4; ++r) {
          float e0 = exp2f(s0[r]);
          float e1 = exp2f(s1[r]);
          ls += e0 + e1;
          p0[r] = (f16)e0;
          p1[r] = (f16)e1;
        }
        lsum[qt] += ls;
        // P[q=l16][key]: keys quad*4+r (tile0), 16+quad*4+r (tile1)
        *(f16x4*)(pw + l16 * 40 + quad * 4)      = p0;
        *(f16x4*)(pw + l16 * 40 + 16 + quad * 4) = p1;
        // A-frag: P[m=l16][kk=quad*8+j]  (in-wave RAW; compiler waits lgkm)
        f16x8 pf = *(const f16x8*)(pw + l16 * 40 + quad * 8);
        oacc[qt][0] = __builtin_amdgcn_mfma_f32_16x16x32_f16(
            pf, vf[c * 2 + 0], oacc[qt][0], 0, 0, 0);
        oacc[qt][1] = __builtin_amdgcn_mfma_f32_16x16x32_f16(
            pf, vf[c * 2 + 1], oacc[qt][1], 0, 0, 0);
      }
    }
  }

  // epilogue: finish lsum (quads hold disjoint key partials), divide, store
#pragma unroll
  for (int qt = 0; qt < 4; ++qt) {
    float ls = lsum[qt];
    ls += __shfl_xor(ls, 16);
    ls += __shfl_xor(ls, 32);
#pragma unroll
    for (int r = 0; r < 4; ++r) {
      float inv = 1.f / __shfl(ls, quad * 4 + r);
      int row = qbase + qt * 16 + quad * 4 + r;
#pragma unroll
      for (int h = 0; h < 2; ++h)
        xo[hb + (size_t)row * DHEAD + h * 16 + l16] =
            (f16)(oacc[qt][h][r] * inv);
    }
  }
}

// ---------------------------------------------------------------------------
// Kernel 3: out = xatt @ Wm^T + bm + residual(q), f32 out. xatt f16 [bth,l,d].
// ---------------------------------------------------------------------------
__global__ __launch_bounds__(256, 4)
void out_proj_kernel(const f16* __restrict__ xatt,
                     const float* __restrict__ Wm,
                     const float* __restrict__ bm,
                     const float* __restrict__ resid,
                     float* __restrict__ out) {
  __shared__ __align__(16) float xs[32][CDIM];
  const int tid = threadIdx.x;
  const int tokbase = blockIdx.x * 32;

#pragma unroll
  for (int u = 0; u < 4; ++u) {
    int idx = u * 256 + tid;  // 8-f16 unit
    int tok = idx >> 5;
    int i = (idx & 31) * 8;
    int gtok = tokbase + tok;
    int bt = gtok >> 10, l = gtok & 1023;
    int h = i >> 5, d = i & 31;
    f16x8 hv = *(const f16x8*)(xatt +
                               (((size_t)bt * HEADS + h) * LSEQ + l) * DHEAD + d);
#pragma unroll
    for (int j = 0; j < 8; ++j) xs[tok][i + j] = (float)hv[j];
  }
  __syncthreads();

  const int c0 = tid & 63;
  const int g  = tid >> 6;

  float acc[4][8];
#pragma unroll
  for (int k = 0; k < 4; ++k)
#pragma unroll
    for (int t = 0; t < 8; ++t) acc[k][t] = 0.f;

  for (int i = 0; i < CDIM; i += 8) {
    float wf[4][8];
#pragma unroll
    for (int k = 0; k < 4; ++k) {
      const float* wr = Wm + (size_t)(c0 + 64 * k) * CDIM + i;
      *(float4*)&wf[k][0] = *(const float4*)wr;
      *(float4*)&wf[k][4] = *(const float4*)(wr + 4);
    }
#pragma unroll
    for (int t = 0; t < 8; ++t) {
      const float* xr = &xs[g * 8 + t][i];
      float4 xa = *(const float4*)xr;
      float4 xb = *(const float4*)(xr + 4);
#pragma unroll
      for (int k = 0; k < 4; ++k) {
        acc[k][t] += wf[k][0] * xa.x + wf[k][1] * xa.y + wf[k][2] * xa.z +
                     wf[k][3] * xa.w + wf[k][4] * xb.x + wf[k][5] * xb.y +
                     wf[k][6] * xb.z + wf[k][7] * xb.w;
      }
    }
  }

#pragma unroll
  for (int k = 0; k < 4; ++k) {
    int ch = c0 + 64 * k;
    float bv = bm[ch];
#pragma unroll
    for (int t = 0; t < 8; ++t) {
      int tok = tokbase + g * 8 + t;
      out[(size_t)tok * CDIM + ch] =
          acc[k][t] + bv + resid[(size_t)tok * CDIM + ch];
    }
  }
}

extern "C" void kernel_launch(void* const* d_in, const int* in_sizes, int n_in,
                              void* d_out, int out_size, void* d_ws,
                              size_t ws_size, hipStream_t stream) {
  const float* q  = (const float*)d_in[0];
  const float* k  = (const float*)d_in[1];
  const float* v  = (const float*)d_in[2];
  const float* Wq = (const float*)d_in[3];
  const float* bq = (const float*)d_in[4];
  const float* Wk = (const float*)d_in[5];
  const float* bk = (const float*)d_in[6];
  const float* Wv = (const float*)d_in[7];
  const float* bv = (const float*)d_in[8];
  const float* Wm = (const float*)d_in[9];
  const float* bm = (const float*)d_in[10];
  float* outp = (float*)d_out;

  f16* ws = (f16*)d_ws;
  const size_t TENS = (size_t)NTOK * CDIM;  // 4194304
  f16* qn = ws;
  f16* kn = ws + TENS;
  f16* vt = ws + 2 * TENS;
  f16* xa = ws + 3 * TENS;

  dim3 blk(256);
  proj_norm_kernel<<<dim3(NTOK / 32), blk, 0, stream>>>(q, Wq, bq, qn, QSCALE, 0);
  proj_norm_kernel<<<dim3(NTOK / 32), blk, 0, stream>>>(k, Wk, bk, kn, 1.0f, 0);
  proj_norm_kernel<<<dim3(NTOK / 32), blk, 0, stream>>>(v, Wv, bv, vt, 1.0f, 1);
  attn_mfma_kernel<<<dim3(512), blk, 0, stream>>>(qn, kn, vt, xa);
  out_proj_kernel<<<dim3(NTOK / 32), blk, 0, stream>>>(xa, Wm, bm, q, outp);
}

// Round 4
// 204.480 us; speedup vs baseline: 3.5857x; 2.0783x over previous
//
#include <hip/hip_runtime.h>
#include <hip/hip_bf16.h>

// Shapes: b=2,t=8,l=1024,c=256,h=8,d=32 -> NTOK=16384, BTH=128
// Inputs/outputs: float32. ws intermediates: _Float16.
// ws layout (f16): qn | kn | vt | xa, each 4194304 elems (8MB) -> 32MB
//   qn/kn/xa: [bth][l][32]; vt TRANSPOSED: [bth][32][l]
//   W-f16 scratch (Wq|Wk|Wv, 3*65536) aliases the xa region: it is consumed
//   by proj_mfma before attn overwrites xa. Stream order guarantees safety.
// qn is pre-scaled by log2(e)/sqrt(32) so attn uses exp2 directly.

#define NTOK  16384
#define CDIM  256
#define LSEQ  1024
#define HEADS 8
#define DHEAD 32

typedef _Float16 f16;
typedef __attribute__((ext_vector_type(2))) _Float16 f16x2;
typedef __attribute__((ext_vector_type(4))) _Float16 f16x4;
typedef __attribute__((ext_vector_type(8))) _Float16 f16x8;
typedef __attribute__((ext_vector_type(4))) float f32x4;

#define QSCALE (0.17677669529663687f * 1.4426950408889634f)  // 1/sqrt(32)*log2e

__device__ __forceinline__ f16x2 pkcvt(float a, float b) {
  auto r = __builtin_amdgcn_cvt_pkrtz(a, b);  // v_cvt_pkrtz_f16_f32
  union { decltype(r) in; f16x2 out; } u;
  u.in = r;
  return u.out;
}

// 8 consecutive f32 at p (32B-aligned) -> f16x8 fragment
__device__ __forceinline__ f16x8 cvt8(const float* p) {
  float4 a = *(const float4*)p;
  float4 b = *(const float4*)(p + 4);
  union { f16x8 v; f16x2 h[4]; } u;
  u.h[0] = pkcvt(a.x, a.y);
  u.h[1] = pkcvt(a.z, a.w);
  u.h[2] = pkcvt(b.x, b.y);
  u.h[3] = pkcvt(b.z, b.w);
  return u.v;
}

// ---------------------------------------------------------------------------
// Kernel 0: convert Wq|Wk|Wv (each 256x256 f32) to f16, packed consecutively.
// ---------------------------------------------------------------------------
__global__ __launch_bounds__(256)
void cvt_w_kernel(const float* __restrict__ Wq, const float* __restrict__ Wk,
                  const float* __restrict__ Wv, f16* __restrict__ dst) {
  const int m = blockIdx.x >> 6;  // matrix index
  const float* src = (m == 0) ? Wq : (m == 1) ? Wk : Wv;
  const int base = (blockIdx.x & 63) * 1024 + threadIdx.x * 4;
  float4 a = *(const float4*)(src + base);
  union { f16x4 v; f16x2 h[2]; } u;
  u.h[0] = pkcvt(a.x, a.y);
  u.h[1] = pkcvt(a.z, a.w);
  *(f16x4*)(dst + m * 65536 + base) = u.v;
}

// ---------------------------------------------------------------------------
// Kernel 1: fused Q/K/V projection + bias + per-head L2-norm via MFMA.
// Grid (256, 3): blockIdx.y selects tensor. Block = 4 waves, 64 tokens;
// wave w computes out-channels 64w..64w+63 (heads 2w, 2w+1) x 64 tokens.
// D[m=och][n=tok] = sum_k W[och][k] * x[tok][k]; both frags contiguous 16B.
// A = W f16 (pre-converted), B = x f32 -> f16 inline. No LDS, no barriers.
// C-layout: col=l16 -> token, row=quad*4+r -> och.
// ---------------------------------------------------------------------------
__global__ __launch_bounds__(256, 3)
void proj_mfma_kernel(const float* __restrict__ xq, const float* __restrict__ xk,
                      const float* __restrict__ xv, const f16* __restrict__ w16,
                      const float* __restrict__ bq, const float* __restrict__ bk,
                      const float* __restrict__ bv,
                      f16* __restrict__ qn, f16* __restrict__ kn,
                      f16* __restrict__ vt) {
  const int which = blockIdx.y;
  const float* x    = (which == 0) ? xq : (which == 1) ? xk : xv;
  const float* bias = (which == 0) ? bq : (which == 1) ? bk : bv;
  const f16* W      = w16 + which * 65536;
  f16* out          = (which == 0) ? qn : (which == 1) ? kn : vt;
  const float scale = (which == 0) ? QSCALE : 1.0f;
  const bool transposed = (which == 2);

  const int tid = threadIdx.x;
  const int wave = tid >> 6, lane = tid & 63;
  const int quad = lane >> 4, l16 = lane & 15;
  const int tokbase = blockIdx.x * 64;
  const int wbase = wave * 64;

  f32x4 acc[4][4];  // [m-tile][n-tile]
#pragma unroll
  for (int mt = 0; mt < 4; ++mt)
#pragma unroll
    for (int nt = 0; nt < 4; ++nt) acc[mt][nt] = (f32x4){0.f, 0.f, 0.f, 0.f};

#pragma unroll
  for (int kk = 0; kk < 8; ++kk) {
    f16x8 af[4], bf[4];
#pragma unroll
    for (int mt = 0; mt < 4; ++mt)
      af[mt] = *(const f16x8*)(W + (size_t)(wbase + mt * 16 + l16) * CDIM +
                               kk * 32 + quad * 8);
#pragma unroll
    for (int nt = 0; nt < 4; ++nt)
      bf[nt] = cvt8(x + (size_t)(tokbase + nt * 16 + l16) * CDIM + kk * 32 +
                    quad * 8);
#pragma unroll
    for (int mt = 0; mt < 4; ++mt)
#pragma unroll
      for (int nt = 0; nt < 4; ++nt)
        acc[mt][nt] = __builtin_amdgcn_mfma_f32_16x16x32_f16(af[mt], bf[nt],
                                                             acc[mt][nt], 0, 0, 0);
  }

  // epilogue: bias -> per-head L2 norm (d spans 2 m-tiles x 4 quads) -> store
  const int bt = tokbase >> 10, l0 = tokbase & 1023;
#pragma unroll
  for (int hh = 0; hh < 2; ++hh) {
    const int h = wave * 2 + hh;
    const size_t hb = (size_t)(bt * HEADS + h) * (LSEQ * DHEAD);
    float4 b0 = *(const float4*)(bias + wbase + hh * 32 + quad * 4);
    float4 b1 = *(const float4*)(bias + wbase + hh * 32 + 16 + quad * 4);
#pragma unroll
    for (int nt = 0; nt < 4; ++nt) {
      f32x4 a0 = acc[hh * 2 + 0][nt];
      f32x4 a1 = acc[hh * 2 + 1][nt];
      float v0[4], v1[4];
      v0[0] = a0[0] + b0.x; v0[1] = a0[1] + b0.y;
      v0[2] = a0[2] + b0.z; v0[3] = a0[3] + b0.w;
      v1[0] = a1[0] + b1.x; v1[1] = a1[1] + b1.y;
      v1[2] = a1[2] + b1.z; v1[3] = a1[3] + b1.w;
      float ss = 0.f;
#pragma unroll
      for (int r = 0; r < 4; ++r) ss += v0[r] * v0[r] + v1[r] * v1[r];
      ss += __shfl_xor(ss, 16);
      ss += __shfl_xor(ss, 32);
      const float inv = scale / fmaxf(sqrtf(ss), 1e-12f);
      const int tok_l = l0 + nt * 16 + l16;
      if (!transposed) {
        f16x4 o0, o1;
#pragma unroll
        for (int r = 0; r < 4; ++r) {
          o0[r] = (f16)(v0[r] * inv);
          o1[r] = (f16)(v1[r] * inv);
        }
        *(f16x4*)(out + hb + (size_t)tok_l * DHEAD + quad * 4) = o0;
        *(f16x4*)(out + hb + (size_t)tok_l * DHEAD + 16 + quad * 4) = o1;
      } else {
#pragma unroll
        for (int r = 0; r < 4; ++r) {
          out[hb + (size_t)(quad * 4 + r) * LSEQ + tok_l] = (f16)(v0[r] * inv);
          out[hb + (size_t)(16 + quad * 4 + r) * LSEQ + tok_l] = (f16)(v1[r] * inv);
        }
      }
    }
  }
}

// ---------------------------------------------------------------------------
// Kernel 2: MFMA attention (unchanged from round 3 — verified).
// ---------------------------------------------------------------------------
__global__ __launch_bounds__(256, 2)
void attn_mfma_kernel(const f16* __restrict__ qn,
                      const f16* __restrict__ kn,
                      const f16* __restrict__ vt,
                      f16* __restrict__ xo) {
  __shared__ f16 pbuf[4][16 * 40];  // 5KB, per-wave private 16x40
  const int tid  = threadIdx.x;
  const int wave = tid >> 6, lane = tid & 63;
  const int quad = lane >> 4, l16 = lane & 15;
  const int bth  = blockIdx.x >> 2;
  const int qbase = ((blockIdx.x & 3) << 8) + wave * 64;
  const size_t hb = (size_t)bth * (LSEQ * DHEAD);
  f16* pw = &pbuf[wave][0];

  f16x8 qf[4];
#pragma unroll
  for (int qt = 0; qt < 4; ++qt)
    qf[qt] = *(const f16x8*)(qn + hb +
                             (size_t)(qbase + qt * 16 + l16) * DHEAD + quad * 8);

  f32x4 oacc[4][2];
  float lsum[4];
#pragma unroll
  for (int qt = 0; qt < 4; ++qt) {
    lsum[qt] = 0.f;
#pragma unroll
    for (int h = 0; h < 2; ++h) oacc[qt][h] = (f32x4){0.f, 0.f, 0.f, 0.f};
  }

  for (int kb = 0; kb < LSEQ; kb += 128) {
    f16x8 kf[8];
#pragma unroll
    for (int t = 0; t < 8; ++t)
      kf[t] = *(const f16x8*)(kn + hb +
                              (size_t)(kb + t * 16 + l16) * DHEAD + quad * 8);
    f16x8 vf[8];
#pragma unroll
    for (int c = 0; c < 4; ++c)
#pragma unroll
      for (int h = 0; h < 2; ++h)
        vf[c * 2 + h] = *(const f16x8*)(vt + hb +
                                        (size_t)(h * 16 + l16) * LSEQ + kb +
                                        c * 32 + quad * 8);

#pragma unroll
    for (int qt = 0; qt < 4; ++qt) {
#pragma unroll
      for (int c = 0; c < 4; ++c) {
        const f32x4 z = {0.f, 0.f, 0.f, 0.f};
        f32x4 s0 = __builtin_amdgcn_mfma_f32_16x16x32_f16(kf[c * 2 + 0],
                                                          qf[qt], z, 0, 0, 0);
        f32x4 s1 = __builtin_amdgcn_mfma_f32_16x16x32_f16(kf[c * 2 + 1],
                                                          qf[qt], z, 0, 0, 0);
        f16x4 p0, p1;
        float ls = 0.f;
#pragma unroll
        for (int r = 0; r < 4; ++r) {
          float e0 = exp2f(s0[r]);
          float e1 = exp2f(s1[r]);
          ls += e0 + e1;
          p0[r] = (f16)e0;
          p1[r] = (f16)e1;
        }
        lsum[qt] += ls;
        *(f16x4*)(pw + l16 * 40 + quad * 4)      = p0;
        *(f16x4*)(pw + l16 * 40 + 16 + quad * 4) = p1;
        f16x8 pf = *(const f16x8*)(pw + l16 * 40 + quad * 8);
        oacc[qt][0] = __builtin_amdgcn_mfma_f32_16x16x32_f16(
            pf, vf[c * 2 + 0], oacc[qt][0], 0, 0, 0);
        oacc[qt][1] = __builtin_amdgcn_mfma_f32_16x16x32_f16(
            pf, vf[c * 2 + 1], oacc[qt][1], 0, 0, 0);
      }
    }
  }

#pragma unroll
  for (int qt = 0; qt < 4; ++qt) {
    float ls = lsum[qt];
    ls += __shfl_xor(ls, 16);
    ls += __shfl_xor(ls, 32);
#pragma unroll
    for (int r = 0; r < 4; ++r) {
      float inv = 1.f / __shfl(ls, quad * 4 + r);
      int row = qbase + qt * 16 + quad * 4 + r;
#pragma unroll
      for (int h = 0; h < 2; ++h)
        xo[hb + (size_t)row * DHEAD + h * 16 + l16] =
            (f16)(oacc[qt][h][r] * inv);
    }
  }
}

// ---------------------------------------------------------------------------
// Kernel 3: out = xatt @ Wm^T + bm + residual, f32 out, via MFMA.
// Same structure as proj_mfma; A = Wm inline f32->f16; k-step kk == head kk
// of xatt ([bth][l][32] is k-contiguous within a head). float4 stores.
// ---------------------------------------------------------------------------
__global__ __launch_bounds__(256, 3)
void out_proj_mfma_kernel(const f16* __restrict__ xatt,
                          const float* __restrict__ Wm,
                          const float* __restrict__ bm,
                          const float* __restrict__ resid,
                          float* __restrict__ out) {
  const int tid = threadIdx.x;
  const int wave = tid >> 6, lane = tid & 63;
  const int quad = lane >> 4, l16 = lane & 15;
  const int tokbase = blockIdx.x * 64;
  const int wbase = wave * 64;
  const int bt = tokbase >> 10, l0 = tokbase & 1023;

  f32x4 acc[4][4];
#pragma unroll
  for (int mt = 0; mt < 4; ++mt)
#pragma unroll
    for (int nt = 0; nt < 4; ++nt) acc[mt][nt] = (f32x4){0.f, 0.f, 0.f, 0.f};

#pragma unroll
  for (int kk = 0; kk < 8; ++kk) {
    const size_t hb = (size_t)(bt * HEADS + kk) * (LSEQ * DHEAD);
    f16x8 af[4], bf[4];
#pragma unroll
    for (int mt = 0; mt < 4; ++mt)
      af[mt] = cvt8(Wm + (size_t)(wbase + mt * 16 + l16) * CDIM + kk * 32 +
                    quad * 8);
#pragma unroll
    for (int nt = 0; nt < 4; ++nt)
      bf[nt] = *(const f16x8*)(xatt + hb +
                               (size_t)(l0 + nt * 16 + l16) * DHEAD + quad * 8);
#pragma unroll
    for (int mt = 0; mt < 4; ++mt)
#pragma unroll
      for (int nt = 0; nt < 4; ++nt)
        acc[mt][nt] = __builtin_amdgcn_mfma_f32_16x16x32_f16(af[mt], bf[nt],
                                                             acc[mt][nt], 0, 0, 0);
  }

#pragma unroll
  for (int mt = 0; mt < 4; ++mt) {
    float4 bv = *(const float4*)(bm + wbase + mt * 16 + quad * 4);
#pragma unroll
    for (int nt = 0; nt < 4; ++nt) {
      const int tok = tokbase + nt * 16 + l16;
      const size_t off = (size_t)tok * CDIM + wbase + mt * 16 + quad * 4;
      float4 rv = *(const float4*)(resid + off);
      float4 o;
      o.x = acc[mt][nt][0] + bv.x + rv.x;
      o.y = acc[mt][nt][1] + bv.y + rv.y;
      o.z = acc[mt][nt][2] + bv.z + rv.z;
      o.w = acc[mt][nt][3] + bv.w + rv.w;
      *(float4*)(out + off) = o;
    }
  }
}

extern "C" void kernel_launch(void* const* d_in, const int* in_sizes, int n_in,
                              void* d_out, int out_size, void* d_ws,
                              size_t ws_size, hipStream_t stream) {
  const float* q  = (const float*)d_in[0];
  const float* k  = (const float*)d_in[1];
  const float* v  = (const float*)d_in[2];
  const float* Wq = (const float*)d_in[3];
  const float* bq = (const float*)d_in[4];
  const float* Wk = (const float*)d_in[5];
  const float* bk = (const float*)d_in[6];
  const float* Wv = (const float*)d_in[7];
  const float* bv = (const float*)d_in[8];
  const float* Wm = (const float*)d_in[9];
  const float* bm = (const float*)d_in[10];
  float* outp = (float*)d_out;

  f16* ws = (f16*)d_ws;
  const size_t TENS = (size_t)NTOK * CDIM;  // 4194304
  f16* qn  = ws;
  f16* kn  = ws + TENS;
  f16* vt  = ws + 2 * TENS;
  f16* xa  = ws + 3 * TENS;
  f16* w16 = xa;  // alias: consumed by proj_mfma before attn writes xa

  dim3 blk(256);
  cvt_w_kernel<<<dim3(192), blk, 0, stream>>>(Wq, Wk, Wv, w16);
  proj_mfma_kernel<<<dim3(256, 3), blk, 0, stream>>>(q, k, v, w16, bq, bk, bv,
                                                     qn, kn, vt);
  attn_mfma_kernel<<<dim3(512), blk, 0, stream>>>(qn, kn, vt, xa);
  out_proj_mfma_kernel<<<dim3(256), blk, 0, stream>>>(xa, Wm, bm, q, outp);
}